// Round 1
// baseline (1933.193 us; speedup 1.0000x reference)
//
#include <hip/hip_runtime.h>

#define B_SZ 4096
#define D_SZ 1024
#define K_SZ 32

typedef _Float16 h16x8 __attribute__((ext_vector_type(8)));
typedef float f32x4 __attribute__((ext_vector_type(4)));
typedef float f32x2 __attribute__((ext_vector_type(2)));
typedef unsigned int u32x2 __attribute__((ext_vector_type(2)));
typedef unsigned int u32x4 __attribute__((ext_vector_type(4)));

// LDS tile: 128 rows x 64 fp16 = 128 B/row. XOR-swizzle the eight 16B slots
// within a row by (row&7) -> conflict-free ds_read_b128 / staged writes.
__device__ __forceinline__ int swz(int row, int byte_in_row) {
    int slot = byte_in_row >> 4;
    int in   = byte_in_row & 15;
    return row * 128 + (((slot ^ (row & 7)) << 4) | in);
}

// fp32 -> fp16 hi + fp16 lo*2^11 (lo scaled to stay normal)
__device__ __forceinline__ void split1(float x, unsigned short& h, unsigned short& l) {
    _Float16 hf = (_Float16)x;
    float hff = (float)hf;
    _Float16 lf = (_Float16)((x - hff) * 2048.0f);
    h = __builtin_bit_cast(unsigned short, hf);
    l = __builtin_bit_cast(unsigned short, lf);
}

// Computes btp[k, b] = sum_{d,e} e1[b,d] W[k,d,e] e2[b,e], accumulated
// (atomicAdd) into out[k*B + b]  ((K,B) row-major flat == output flat order).
__global__ __launch_bounds__(256, 2)
void ntl_bilinear(const float* __restrict__ e1,
                  const float* __restrict__ e2,
                  const float* __restrict__ W,
                  float* __restrict__ out) {
    __shared__ __align__(16) char smem[65536];
    char* const Ah = smem;
    char* const Al = smem + 16384;
    char* const Bh = smem + 32768;
    char* const Bl = smem + 49152;

    const int bid = blockIdx.x;
    const int k   = bid >> 8;          // 256 blocks per k (k-major: W[k] stays hot in L2)
    const int rem = bid & 255;
    const int b0  = (rem >> 3) * 128;  // 32 b-tiles
    const int e0  = (rem & 7) * 128;   // 8 e-tiles

    const int t  = threadIdx.x;
    const int l  = t & 63;
    const int w  = t >> 6;
    const int wr = (w >> 1) * 64;      // wave row offset in tile
    const int wc = (w & 1) * 64;       // wave col offset in tile
    const int lrow = l & 15;
    const int lq   = l >> 4;

    f32x4 acc1[4][4];   // hi*hi
    f32x4 acc2[4][4];   // hi*lo' + lo'*hi   (scale 2^11)
    #pragma unroll
    for (int m = 0; m < 4; ++m)
        #pragma unroll
        for (int n = 0; n < 4; ++n) {
            acc1[m][n] = f32x4{0.f, 0.f, 0.f, 0.f};
            acc2[m][n] = f32x4{0.f, 0.f, 0.f, 0.f};
        }

    // staging roles
    const int sa_row = t >> 4;         // 0..15
    const int sa_cg  = (t & 15) * 4;   // float offset within 64-wide k-slab
    const int sb_e   = t & 127;        // e column
    const int sb_dg  = t >> 7;         // 0..1 -> 32 d's each

    const float* const e1b = e1 + (size_t)b0 * D_SZ;
    const float* const wb  = W + ((size_t)k * D_SZ) * D_SZ + e0 + sb_e;

    for (int kt = 0; kt < D_SZ / 64; ++kt) {
        const int d0 = kt * 64;

        // ---- stage A: e1[b0..b0+127][d0..d0+63] -> Ah/Al [row][k] ----
        #pragma unroll
        for (int p = 0; p < 8; ++p) {
            const int r = sa_row + p * 16;
            f32x4 v = *(const f32x4*)(e1b + (size_t)r * D_SZ + d0 + sa_cg);
            unsigned short hh[4], ll[4];
            #pragma unroll
            for (int q = 0; q < 4; ++q) split1(v[q], hh[q], ll[q]);
            u32x2 hv = { (unsigned)hh[0] | ((unsigned)hh[1] << 16),
                         (unsigned)hh[2] | ((unsigned)hh[3] << 16) };
            u32x2 lv = { (unsigned)ll[0] | ((unsigned)ll[1] << 16),
                         (unsigned)ll[2] | ((unsigned)ll[3] << 16) };
            const int ad = swz(r, sa_cg * 2);
            *(u32x2*)(Ah + ad) = hv;
            *(u32x2*)(Al + ad) = lv;
        }

        // ---- stage B: W[k][d0..d0+63][e0..e0+127] transposed -> Bh/Bl [e][d] ----
        {
            const float* ws2 = wb + (size_t)(d0 + sb_dg * 32) * D_SZ;
            #pragma unroll
            for (int g = 0; g < 4; ++g) {
                unsigned short hh[8], ll[8];
                #pragma unroll
                for (int i = 0; i < 8; ++i)
                    split1(ws2[(size_t)(g * 8 + i) * D_SZ], hh[i], ll[i]);
                u32x4 hv = { (unsigned)hh[0] | ((unsigned)hh[1] << 16),
                             (unsigned)hh[2] | ((unsigned)hh[3] << 16),
                             (unsigned)hh[4] | ((unsigned)hh[5] << 16),
                             (unsigned)hh[6] | ((unsigned)hh[7] << 16) };
                u32x4 lv = { (unsigned)ll[0] | ((unsigned)ll[1] << 16),
                             (unsigned)ll[2] | ((unsigned)ll[3] << 16),
                             (unsigned)ll[4] | ((unsigned)ll[5] << 16),
                             (unsigned)ll[6] | ((unsigned)ll[7] << 16) };
                const int ad = swz(sb_e, (sb_dg * 32 + g * 8) * 2);
                *(u32x4*)(Bh + ad) = hv;
                *(u32x4*)(Bl + ad) = lv;
            }
        }

        __syncthreads();

        // ---- compute: 3-pass fp16 split MFMA ----
        #pragma unroll
        for (int kk = 0; kk < 2; ++kk) {
            const int kb = kk * 64 + lq * 16;  // byte offset: 8 consecutive k per lane
            h16x8 a_h[4], a_l[4];
            #pragma unroll
            for (int m = 0; m < 4; ++m) {
                const int ad = swz(wr + m * 16 + lrow, kb);
                a_h[m] = *(const h16x8*)(Ah + ad);
                a_l[m] = *(const h16x8*)(Al + ad);
            }
            #pragma unroll
            for (int n = 0; n < 4; ++n) {
                const int bd = swz(wc + n * 16 + lrow, kb);
                h16x8 b_h = *(const h16x8*)(Bh + bd);
                h16x8 b_l = *(const h16x8*)(Bl + bd);
                #pragma unroll
                for (int m = 0; m < 4; ++m) {
                    acc1[m][n] = __builtin_amdgcn_mfma_f32_16x16x32_f16(a_h[m], b_h, acc1[m][n], 0, 0, 0);
                    acc2[m][n] = __builtin_amdgcn_mfma_f32_16x16x32_f16(a_h[m], b_l, acc2[m][n], 0, 0, 0);
                    acc2[m][n] = __builtin_amdgcn_mfma_f32_16x16x32_f16(a_l[m], b_h, acc2[m][n], 0, 0, 0);
                }
            }
        }

        __syncthreads();
    }

    // ---- epilogue: T .* e2, reduce over this block's 128 e-columns ----
    // C/D layout (m89): col = lane&15, row = (lane>>4)*4 + j
    float rsum[16];
    #pragma unroll
    for (int i = 0; i < 16; ++i) rsum[i] = 0.f;

    #pragma unroll
    for (int m = 0; m < 4; ++m) {
        #pragma unroll
        for (int n = 0; n < 4; ++n) {
            const int col = e0 + wc + n * 16 + lrow;
            #pragma unroll
            for (int j = 0; j < 4; ++j) {
                const int row = b0 + wr + m * 16 + lq * 4 + j;
                float tv = acc1[m][n][j] + acc2[m][n][j] * (1.0f / 2048.0f);
                rsum[m * 4 + j] += tv * e2[(size_t)row * D_SZ + col];
            }
        }
    }

    #pragma unroll
    for (int i = 0; i < 16; ++i) {
        float v = rsum[i];
        v += __shfl_xor(v, 1, 16);
        v += __shfl_xor(v, 2, 16);
        v += __shfl_xor(v, 4, 16);
        v += __shfl_xor(v, 8, 16);
        if (lrow == 0) {
            const int row = b0 + wr + (i >> 2) * 16 + lq * 4 + (i & 3);
            atomicAdd(out + (size_t)k * B_SZ + row, v);
        }
    }
}

// ff = concat(e1,e2) @ V, accumulated into out[r*K + c] ((B,K) flat order).
__global__ __launch_bounds__(256)
void ntl_ff(const float* __restrict__ e1, const float* __restrict__ e2,
            const float* __restrict__ V, float* __restrict__ out) {
    __shared__ float vt[32 * 258];     // V chunk transposed, stride 258 (8B-aligned rows, conflict-light)
    const int t  = threadIdx.x;
    const int c  = t & 31;
    const int rl = t >> 5;
    const int r  = blockIdx.x * 8 + rl;

    float acc = 0.f;
    for (int j0 = 0; j0 < 2 * D_SZ; j0 += 256) {
        __syncthreads();
        #pragma unroll
        for (int i = 0; i < 32; ++i) {
            const int f = i * 256 + t;
            vt[(f & 31) * 258 + (f >> 5)] = V[(size_t)j0 * K_SZ + f];
        }
        __syncthreads();
        const float* src = (j0 < D_SZ) ? (e1 + (size_t)r * D_SZ + j0)
                                       : (e2 + (size_t)r * D_SZ + (j0 - D_SZ));
        #pragma unroll 8
        for (int jj = 0; jj < 256; jj += 2) {
            f32x2 a  = *(const f32x2*)(src + jj);
            f32x2 vv = *(const f32x2*)(&vt[c * 258 + jj]);
            acc += a[0] * vv[0] + a[1] * vv[1];
        }
    }
    out[(size_t)r * K_SZ + c] += acc;   // single owner per element; stream-ordered after bilinear
}

__global__ void ntl_sumb(const float* __restrict__ b, float* __restrict__ ws) {
    __shared__ float red[256];
    const int t = threadIdx.x;
    red[t] = b[t] + b[t + 256] + b[t + 512] + b[t + 768];
    __syncthreads();
    for (int s = 128; s > 0; s >>= 1) {
        if (t < s) red[t] += red[t + s];
        __syncthreads();
    }
    if (t == 0) ws[0] = red[0];
}

__global__ void ntl_tanh(float* __restrict__ out, const float* __restrict__ ws) {
    const int p = blockIdx.x * 256 + threadIdx.x;
    out[p] = tanhf(out[p] + ws[0]);
}

extern "C" void kernel_launch(void* const* d_in, const int* in_sizes, int n_in,
                              void* d_out, int out_size, void* d_ws, size_t ws_size,
                              hipStream_t stream) {
    const float* e1 = (const float*)d_in[0];
    const float* e2 = (const float*)d_in[1];
    const float* W  = (const float*)d_in[2];
    const float* V  = (const float*)d_in[3];
    const float* b  = (const float*)d_in[4];
    float* out = (float*)d_out;
    float* ws  = (float*)d_ws;

    hipMemsetAsync(d_out, 0, (size_t)B_SZ * K_SZ * sizeof(float), stream);
    ntl_sumb<<<1, 256, 0, stream>>>(b, ws);
    ntl_bilinear<<<dim3(32 * 256), dim3(256), 0, stream>>>(e1, e2, W, out);
    ntl_ff<<<dim3(B_SZ / 8), dim3(256), 0, stream>>>(e1, e2, V, out);
    ntl_tanh<<<dim3((B_SZ * K_SZ) / 256), dim3(256), 0, stream>>>(out, ws);
}

// Round 2
// 820.165 us; speedup vs baseline: 2.3571x; 2.3571x over previous
//
#include <hip/hip_runtime.h>

#define B_SZ 4096
#define D_SZ 1024
#define K_SZ 32

typedef _Float16 h16x8 __attribute__((ext_vector_type(8)));
typedef float f32x4 __attribute__((ext_vector_type(4)));
typedef float f32x2 __attribute__((ext_vector_type(2)));
typedef unsigned int u32x2 __attribute__((ext_vector_type(2)));
typedef unsigned int u32x4 __attribute__((ext_vector_type(4)));
typedef unsigned short u16x4 __attribute__((ext_vector_type(4)));

// async global->LDS, 16B per lane
#define GLOAD16(gp, sp) __builtin_amdgcn_global_load_lds( \
    (const __attribute__((address_space(1))) void*)(gp),  \
    (__attribute__((address_space(3))) void*)(sp), 16, 0, 0)

// fp32 -> fp16 hi + fp16 lo*2^11 (lo scaled to stay normal)
__device__ __forceinline__ void split1(float x, _Float16& h, _Float16& l) {
    h = (_Float16)x;
    l = (_Float16)((x - (float)h) * 2048.0f);
}

// ---------------- prepass: W[k][d][e] f32 -> Wt_h/Wt_l[k][e][d] fp16 ----------------
__global__ __launch_bounds__(256)
void ntl_prep_w(const float* __restrict__ W,
                _Float16* __restrict__ Wh, _Float16* __restrict__ Wl) {
    __shared__ float tile[64 * 69];       // [d_local][e_local], stride 69 (conflict-light)
    const int bid = blockIdx.x;
    const int k  = bid >> 8;
    const int d0 = ((bid >> 4) & 15) << 6;
    const int e0 = (bid & 15) << 6;
    const int t  = threadIdx.x;
    const int r  = t >> 4;                 // 0..15
    const int c4 = (t & 15) << 2;          // 0,4,..60

    const float* src = W + ((size_t)k * D_SZ + d0) * D_SZ + e0;
    #pragma unroll
    for (int p = 0; p < 4; ++p) {
        f32x4 v = *(const f32x4*)(src + (size_t)(p * 16 + r) * D_SZ + c4);
        float* dst = &tile[(p * 16 + r) * 69 + c4];
        dst[0] = v[0]; dst[1] = v[1]; dst[2] = v[2]; dst[3] = v[3];
    }
    __syncthreads();
    #pragma unroll
    for (int p = 0; p < 4; ++p) {
        const int e = p * 16 + r;
        u16x4 hh, ll;
        #pragma unroll
        for (int q = 0; q < 4; ++q) {
            float v = tile[(c4 + q) * 69 + e];
            _Float16 h, l;
            split1(v, h, l);
            hh[q] = __builtin_bit_cast(unsigned short, h);
            ll[q] = __builtin_bit_cast(unsigned short, l);
        }
        const size_t o = ((size_t)k * D_SZ + e0 + e) * D_SZ + d0 + c4;
        *(u16x4*)(Wh + o) = hh;
        *(u16x4*)(Wl + o) = ll;
    }
}

// ---------------- prepass: e1 f32 -> e1_h/e1_l fp16 ----------------
__global__ __launch_bounds__(256)
void ntl_prep_e(const float* __restrict__ e1,
                _Float16* __restrict__ eh, _Float16* __restrict__ el) {
    const size_t i = ((size_t)blockIdx.x * 256 + threadIdx.x) * 4;
    f32x4 v = *(const f32x4*)(e1 + i);
    u16x4 hh, ll;
    #pragma unroll
    for (int q = 0; q < 4; ++q) {
        _Float16 h, l;
        split1(v[q], h, l);
        hh[q] = __builtin_bit_cast(unsigned short, h);
        ll[q] = __builtin_bit_cast(unsigned short, l);
    }
    *(u16x4*)(eh + i) = hh;
    *(u16x4*)(el + i) = ll;
}

// ---------------- main: btp[k,b] += sum_{d,e} e1 W e2, m97-style GEMM ----------------
// LDS tiles [row][64] fp16 (128B rows), linear dest for global_load_lds;
// XOR slot-swizzle realized by pre-swizzling the GLOBAL source column (rule #21).
__global__ __launch_bounds__(256, 2)
void ntl_bilinear2(const _Float16* __restrict__ eh, const _Float16* __restrict__ el,
                   const _Float16* __restrict__ Wh, const _Float16* __restrict__ Wl,
                   const float* __restrict__ e2, float* __restrict__ out) {
    __shared__ __align__(16) _Float16 lds[4 * 128 * 64];   // Ah|Al|Bh|Bl, 16KB each
    char* const base = (char*)lds;

    const int bid = blockIdx.x;
    const int k   = bid >> 8;          // k-major: W[k] slices stay hot in L2
    const int rem = bid & 255;
    const int b0  = (rem >> 3) * 128;
    const int e0  = (rem & 7) * 128;

    const int t  = threadIdx.x;
    const int l  = t & 63;
    const int w  = t >> 6;
    const int wr = (w >> 1) * 64;
    const int wc = (w & 1) * 64;
    const int lrow = l & 15;
    const int lq   = l >> 4;

    f32x4 acc1[4][4];   // hi*hi
    f32x4 acc2[4][4];   // hi*lo' + lo'*hi  (scale 2^11)
    #pragma unroll
    for (int m = 0; m < 4; ++m)
        #pragma unroll
        for (int n = 0; n < 4; ++n) {
            acc1[m][n] = f32x4{0.f, 0.f, 0.f, 0.f};
            acc2[m][n] = f32x4{0.f, 0.f, 0.f, 0.f};
        }

    // staging: lane l covers row (l>>3) of its wave's 8-row group, slot (l&7);
    // global column slot is XOR'd so the linear LDS write lands "swizzled".
    const int srow  = l >> 3;
    const int gslot = (l & 7) ^ srow;
    const size_t aoff = (size_t)(b0 + w * 8 + srow) * D_SZ + gslot * 8;
    const size_t boff = ((size_t)k * D_SZ + e0 + w * 8 + srow) * D_SZ + gslot * 8;
    const _Float16* gAh = eh + aoff;
    const _Float16* gAl = el + aoff;
    const _Float16* gBh = Wh + boff;
    const _Float16* gBl = Wl + boff;

    for (int kt = 0; kt < D_SZ / 64; ++kt) {
        const int d0 = kt * 64;
        #pragma unroll
        for (int p = 0; p < 4; ++p) {
            const size_t ro = (size_t)p * 32 * D_SZ + d0;
            char* sb_ = base + p * 4096 + w * 1024;   // wave-uniform LDS dest
            GLOAD16(gAh + ro, sb_);
            GLOAD16(gAl + ro, sb_ + 16384);
            GLOAD16(gBh + ro, sb_ + 32768);
            GLOAD16(gBl + ro, sb_ + 49152);
        }
        __syncthreads();   // compiler emits vmcnt(0) drain before s_barrier

        #pragma unroll
        for (int kk = 0; kk < 2; ++kk) {
            h16x8 a_h[4], a_l[4];
            #pragma unroll
            for (int m = 0; m < 4; ++m) {
                const int r = wr + m * 16 + lrow;
                const int off = r * 128 + (((kk * 4 + lq) ^ (r & 7)) << 4);
                a_h[m] = *(const h16x8*)(base + off);
                a_l[m] = *(const h16x8*)(base + 16384 + off);
            }
            #pragma unroll
            for (int n = 0; n < 4; ++n) {
                const int r = wc + n * 16 + lrow;
                const int off = r * 128 + (((kk * 4 + lq) ^ (r & 7)) << 4);
                h16x8 b_h = *(const h16x8*)(base + 32768 + off);
                h16x8 b_l = *(const h16x8*)(base + 49152 + off);
                #pragma unroll
                for (int m = 0; m < 4; ++m) {
                    acc1[m][n] = __builtin_amdgcn_mfma_f32_16x16x32_f16(a_h[m], b_h, acc1[m][n], 0, 0, 0);
                    acc2[m][n] = __builtin_amdgcn_mfma_f32_16x16x32_f16(a_h[m], b_l, acc2[m][n], 0, 0, 0);
                    acc2[m][n] = __builtin_amdgcn_mfma_f32_16x16x32_f16(a_l[m], b_h, acc2[m][n], 0, 0, 0);
                }
            }
        }
        __syncthreads();
    }

    // ---- epilogue: T .* e2, reduce over this block's 128 e-columns ----
    // C/D layout (m89): col = lane&15, row = (lane>>4)*4 + j
    float rsum[16];
    #pragma unroll
    for (int i = 0; i < 16; ++i) rsum[i] = 0.f;

    #pragma unroll
    for (int m = 0; m < 4; ++m) {
        #pragma unroll
        for (int n = 0; n < 4; ++n) {
            const int col = e0 + wc + n * 16 + lrow;
            #pragma unroll
            for (int j = 0; j < 4; ++j) {
                const int row = b0 + wr + m * 16 + lq * 4 + j;
                float tv = acc1[m][n][j] + acc2[m][n][j] * (1.0f / 2048.0f);
                rsum[m * 4 + j] += tv * e2[(size_t)row * D_SZ + col];
            }
        }
    }

    #pragma unroll
    for (int i = 0; i < 16; ++i) {
        float v = rsum[i];
        v += __shfl_xor(v, 1, 16);
        v += __shfl_xor(v, 2, 16);
        v += __shfl_xor(v, 4, 16);
        v += __shfl_xor(v, 8, 16);
        if (lrow == 0) {
            const int row = b0 + wr + (i >> 2) * 16 + lq * 4 + (i & 3);
            atomicAdd(out + (size_t)k * B_SZ + row, v);
        }
    }
}

// ================= fallback path (round-1 bilinear, used if ws too small) =================
__device__ __forceinline__ int swz_fb(int row, int byte_in_row) {
    int slot = byte_in_row >> 4;
    int in   = byte_in_row & 15;
    return row * 128 + (((slot ^ (row & 7)) << 4) | in);
}
__device__ __forceinline__ void split_fb(float x, unsigned short& h, unsigned short& l) {
    _Float16 hf = (_Float16)x;
    float hff = (float)hf;
    _Float16 lf = (_Float16)((x - hff) * 2048.0f);
    h = __builtin_bit_cast(unsigned short, hf);
    l = __builtin_bit_cast(unsigned short, lf);
}
__global__ __launch_bounds__(256, 2)
void ntl_bilinear_fb(const float* __restrict__ e1, const float* __restrict__ e2,
                     const float* __restrict__ W, float* __restrict__ out) {
    __shared__ __align__(16) char smem[65536];
    char* const Ah = smem;
    char* const Al = smem + 16384;
    char* const Bh = smem + 32768;
    char* const Bl = smem + 49152;
    const int bid = blockIdx.x;
    const int k   = bid >> 8;
    const int rem = bid & 255;
    const int b0  = (rem >> 3) * 128;
    const int e0  = (rem & 7) * 128;
    const int t  = threadIdx.x;
    const int l  = t & 63;
    const int w  = t >> 6;
    const int wr = (w >> 1) * 64;
    const int wc = (w & 1) * 64;
    const int lrow = l & 15;
    const int lq   = l >> 4;
    f32x4 acc1[4][4], acc2[4][4];
    #pragma unroll
    for (int m = 0; m < 4; ++m)
        #pragma unroll
        for (int n = 0; n < 4; ++n) {
            acc1[m][n] = f32x4{0.f, 0.f, 0.f, 0.f};
            acc2[m][n] = f32x4{0.f, 0.f, 0.f, 0.f};
        }
    const int sa_row = t >> 4;
    const int sa_cg  = (t & 15) * 4;
    const int sb_e   = t & 127;
    const int sb_dg  = t >> 7;
    const float* const e1b = e1 + (size_t)b0 * D_SZ;
    const float* const wb  = W + ((size_t)k * D_SZ) * D_SZ + e0 + sb_e;
    for (int kt = 0; kt < D_SZ / 64; ++kt) {
        const int d0 = kt * 64;
        #pragma unroll
        for (int p = 0; p < 8; ++p) {
            const int r = sa_row + p * 16;
            f32x4 v = *(const f32x4*)(e1b + (size_t)r * D_SZ + d0 + sa_cg);
            unsigned short hh[4], ll[4];
            #pragma unroll
            for (int q = 0; q < 4; ++q) split_fb(v[q], hh[q], ll[q]);
            u32x2 hv = { (unsigned)hh[0] | ((unsigned)hh[1] << 16),
                         (unsigned)hh[2] | ((unsigned)hh[3] << 16) };
            u32x2 lv = { (unsigned)ll[0] | ((unsigned)ll[1] << 16),
                         (unsigned)ll[2] | ((unsigned)ll[3] << 16) };
            const int ad = swz_fb(r, sa_cg * 2);
            *(u32x2*)(Ah + ad) = hv;
            *(u32x2*)(Al + ad) = lv;
        }
        {
            const float* ws2 = wb + (size_t)(d0 + sb_dg * 32) * D_SZ;
            #pragma unroll
            for (int g = 0; g < 4; ++g) {
                unsigned short hh[8], ll[8];
                #pragma unroll
                for (int i = 0; i < 8; ++i)
                    split_fb(ws2[(size_t)(g * 8 + i) * D_SZ], hh[i], ll[i]);
                u32x4 hv = { (unsigned)hh[0] | ((unsigned)hh[1] << 16),
                             (unsigned)hh[2] | ((unsigned)hh[3] << 16),
                             (unsigned)hh[4] | ((unsigned)hh[5] << 16),
                             (unsigned)hh[6] | ((unsigned)hh[7] << 16) };
                u32x4 lv = { (unsigned)ll[0] | ((unsigned)ll[1] << 16),
                             (unsigned)ll[2] | ((unsigned)ll[3] << 16),
                             (unsigned)ll[4] | ((unsigned)ll[5] << 16),
                             (unsigned)ll[6] | ((unsigned)ll[7] << 16) };
                const int ad = swz_fb(sb_e, (sb_dg * 32 + g * 8) * 2);
                *(u32x4*)(Bh + ad) = hv;
                *(u32x4*)(Bl + ad) = lv;
            }
        }
        __syncthreads();
        #pragma unroll
        for (int kk = 0; kk < 2; ++kk) {
            const int kb = kk * 64 + lq * 16;
            h16x8 a_h[4], a_l[4];
            #pragma unroll
            for (int m = 0; m < 4; ++m) {
                const int ad = swz_fb(wr + m * 16 + lrow, kb);
                a_h[m] = *(const h16x8*)(Ah + ad);
                a_l[m] = *(const h16x8*)(Al + ad);
            }
            #pragma unroll
            for (int n = 0; n < 4; ++n) {
                const int bd = swz_fb(wc + n * 16 + lrow, kb);
                h16x8 b_h = *(const h16x8*)(Bh + bd);
                h16x8 b_l = *(const h16x8*)(Bl + bd);
                #pragma unroll
                for (int m = 0; m < 4; ++m) {
                    acc1[m][n] = __builtin_amdgcn_mfma_f32_16x16x32_f16(a_h[m], b_h, acc1[m][n], 0, 0, 0);
                    acc2[m][n] = __builtin_amdgcn_mfma_f32_16x16x32_f16(a_h[m], b_l, acc2[m][n], 0, 0, 0);
                    acc2[m][n] = __builtin_amdgcn_mfma_f32_16x16x32_f16(a_l[m], b_h, acc2[m][n], 0, 0, 0);
                }
            }
        }
        __syncthreads();
    }
    float rsum[16];
    #pragma unroll
    for (int i = 0; i < 16; ++i) rsum[i] = 0.f;
    #pragma unroll
    for (int m = 0; m < 4; ++m) {
        #pragma unroll
        for (int n = 0; n < 4; ++n) {
            const int col = e0 + wc + n * 16 + lrow;
            #pragma unroll
            for (int j = 0; j < 4; ++j) {
                const int row = b0 + wr + m * 16 + lq * 4 + j;
                float tv = acc1[m][n][j] + acc2[m][n][j] * (1.0f / 2048.0f);
                rsum[m * 4 + j] += tv * e2[(size_t)row * D_SZ + col];
            }
        }
    }
    #pragma unroll
    for (int i = 0; i < 16; ++i) {
        float v = rsum[i];
        v += __shfl_xor(v, 1, 16);
        v += __shfl_xor(v, 2, 16);
        v += __shfl_xor(v, 4, 16);
        v += __shfl_xor(v, 8, 16);
        if (lrow == 0) {
            const int row = b0 + wr + (i >> 2) * 16 + lq * 4 + (i & 3);
            atomicAdd(out + (size_t)k * B_SZ + row, v);
        }
    }
}

// ---------------- ff / sumb / tanh ----------------
__global__ __launch_bounds__(256)
void ntl_ff(const float* __restrict__ e1, const float* __restrict__ e2,
            const float* __restrict__ V, float* __restrict__ out) {
    __shared__ float vt[32 * 258];
    const int t  = threadIdx.x;
    const int c  = t & 31;
    const int rl = t >> 5;
    const int r  = blockIdx.x * 8 + rl;
    float acc = 0.f;
    for (int j0 = 0; j0 < 2 * D_SZ; j0 += 256) {
        __syncthreads();
        #pragma unroll
        for (int i = 0; i < 32; ++i) {
            const int f = i * 256 + t;
            vt[(f & 31) * 258 + (f >> 5)] = V[(size_t)j0 * K_SZ + f];
        }
        __syncthreads();
        const float* src = (j0 < D_SZ) ? (e1 + (size_t)r * D_SZ + j0)
                                       : (e2 + (size_t)r * D_SZ + (j0 - D_SZ));
        #pragma unroll 8
        for (int jj = 0; jj < 256; jj += 2) {
            f32x2 a  = *(const f32x2*)(src + jj);
            f32x2 vv = *(const f32x2*)(&vt[c * 258 + jj]);
            acc += a[0] * vv[0] + a[1] * vv[1];
        }
    }
    out[(size_t)r * K_SZ + c] += acc;
}

__global__ void ntl_sumb(const float* __restrict__ b, float* __restrict__ ws) {
    __shared__ float red[256];
    const int t = threadIdx.x;
    red[t] = b[t] + b[t + 256] + b[t + 512] + b[t + 768];
    __syncthreads();
    for (int s = 128; s > 0; s >>= 1) {
        if (t < s) red[t] += red[t + s];
        __syncthreads();
    }
    if (t == 0) ws[0] = red[0];
}

__global__ void ntl_tanh(float* __restrict__ out, const float* __restrict__ ws) {
    const int p = blockIdx.x * 256 + threadIdx.x;
    out[p] = tanhf(out[p] + ws[0]);
}

extern "C" void kernel_launch(void* const* d_in, const int* in_sizes, int n_in,
                              void* d_out, int out_size, void* d_ws, size_t ws_size,
                              hipStream_t stream) {
    const float* e1 = (const float*)d_in[0];
    const float* e2 = (const float*)d_in[1];
    const float* W  = (const float*)d_in[2];
    const float* V  = (const float*)d_in[3];
    const float* b  = (const float*)d_in[4];
    float* out = (float*)d_out;

    const size_t WT = (size_t)K_SZ * D_SZ * D_SZ;   // W elements
    const size_t ET = (size_t)B_SZ * D_SZ;          // e1 elements
    const size_t need = (2 * WT + 2 * ET) * sizeof(_Float16) + 16;

    hipMemsetAsync(d_out, 0, (size_t)B_SZ * K_SZ * sizeof(float), stream);

    if (ws_size >= need) {
        _Float16* Wh = (_Float16*)d_ws;
        _Float16* Wl = Wh + WT;
        _Float16* eh = Wl + WT;
        _Float16* el = eh + ET;
        float* sb = (float*)(el + ET);
        ntl_sumb<<<1, 256, 0, stream>>>(b, sb);
        ntl_prep_w<<<dim3(K_SZ * 256), dim3(256), 0, stream>>>(W, Wh, Wl);
        ntl_prep_e<<<dim3((int)(ET / 1024)), dim3(256), 0, stream>>>(e1, eh, el);
        ntl_bilinear2<<<dim3(K_SZ * 256), dim3(256), 0, stream>>>(eh, el, Wh, Wl, e2, out);
        ntl_ff<<<dim3(B_SZ / 8), dim3(256), 0, stream>>>(e1, e2, V, out);
        ntl_tanh<<<dim3((B_SZ * K_SZ) / 256), dim3(256), 0, stream>>>(out, sb);
    } else {
        float* sb = (float*)d_ws;
        ntl_sumb<<<1, 256, 0, stream>>>(b, sb);
        ntl_bilinear_fb<<<dim3(K_SZ * 256), dim3(256), 0, stream>>>(e1, e2, W, out);
        ntl_ff<<<dim3(B_SZ / 8), dim3(256), 0, stream>>>(e1, e2, V, out);
        ntl_tanh<<<dim3((B_SZ * K_SZ) / 256), dim3(256), 0, stream>>>(out, sb);
    }
}